// Round 11
// baseline (102.526 us; speedup 1.0000x reference)
//
#include <hip/hip_runtime.h>
#include <hip/hip_bf16.h>

// NT-Xent (SimCLR) loss, B=4096, D=256, N=8192, T=0.5.
// loss = [ sum_i log(sum_{j!=i} exp(sim_ij * 2)) - 4 * sum_{i<B} pos_i ] / N
// sim symmetric: upper-triangle 256x256 tiles (528 of 1024). 1024-thread
// blocks, 16 waves (4x4), each wave = r8's verified 64x64 job (acc 2x2 of
// 32x32x16 MFMA, barrier-free L1/L2 fragment streaming, 1-deep prefetch).
// 4-way cross-wave L1 sharing on both operands cuts TA traffic ~4x vs r8
// (532 MB -> ~135 MB unique): r8/r3 both measured ~34 us = TA-BW-bound.

constexpr int BB = 4096;                 // batch
constexpr int NN = 8192;                 // 2*batch
constexpr int DD = 256;                  // feature dim
constexpr int TS = 256;                  // tile edge
constexpr int NT = NN / TS;              // 32 tile rows/cols
constexpr int NBLK = NT * (NT + 1) / 2;  // 528 = 8*66
constexpr int KSTEPS = DD / 16;          // 16 MFMA k-steps

typedef _Float16 half4v __attribute__((ext_vector_type(4)));
typedef _Float16 half8v __attribute__((ext_vector_type(8)));
typedef float floatx16 __attribute__((ext_vector_type(16)));

// ---------------- Kernel 1: normalize -> fragment-ordered f16 (r8 verbatim) -
// Zf granule (g*16+ks)*64 + lm + 32*lh holds halfs [16ks+8lh, +8) of row
// 32g+lm. A wave's fragment load = 1 KB contiguous.
__global__ __launch_bounds__(256) void nt_normalize(
    const float* __restrict__ zi, const float* __restrict__ zj,
    _Float16* __restrict__ Zf, float* __restrict__ pos,
    float* __restrict__ rowsum)
{
    __shared__ _Float16 sZ[2][16 * 64 * 8];   // 2 groups x 1024 granules = 32 KB
    const int tid = threadIdx.x;
    const int pr  = tid >> 3;     // row within group, 0..31
    const int sub = tid & 7;      // 8 threads per row
    const int p   = blockIdx.x * 32 + pr;     // pair index, < BB

    if (blockIdx.x < 32) rowsum[blockIdx.x * 256 + tid] = 0.f;

    const float4* ai = (const float4*)(zi + (size_t)p * DD);
    const float4* bj = (const float4*)(zj + (size_t)p * DD);
    float4 av[8], bv[8];
    float ssi = 0.f, ssj = 0.f, dd = 0.f;
#pragma unroll
    for (int t = 0; t < 8; ++t) {
        av[t] = ai[sub + 8 * t];
        bv[t] = bj[sub + 8 * t];
        ssi += av[t].x*av[t].x + av[t].y*av[t].y + av[t].z*av[t].z + av[t].w*av[t].w;
        ssj += bv[t].x*bv[t].x + bv[t].y*bv[t].y + bv[t].z*bv[t].z + bv[t].w*bv[t].w;
        dd  += av[t].x*bv[t].x + av[t].y*bv[t].y + av[t].z*bv[t].z + av[t].w*bv[t].w;
    }
#pragma unroll
    for (int off = 1; off < 8; off <<= 1) {
        ssi += __shfl_xor(ssi, off);
        ssj += __shfl_xor(ssj, off);
        dd  += __shfl_xor(dd,  off);
    }
    const float invi = rsqrtf(ssi);
    const float invj = rsqrtf(ssj);
    if (sub == 0) pos[p] = dd * invi * invj;

#pragma unroll
    for (int t = 0; t < 8; ++t) {
        const int gi = (2 * t + (sub >> 2)) * 64 + pr + 32 * ((sub >> 1) & 1);
        const int wo = 4 * (sub & 1);
        half4v hi, hj;
        hi.x = (_Float16)(av[t].x * invi); hi.y = (_Float16)(av[t].y * invi);
        hi.z = (_Float16)(av[t].z * invi); hi.w = (_Float16)(av[t].w * invi);
        hj.x = (_Float16)(bv[t].x * invj); hj.y = (_Float16)(bv[t].y * invj);
        hj.z = (_Float16)(bv[t].z * invj); hj.w = (_Float16)(bv[t].w * invj);
        *(half4v*)&sZ[0][gi * 8 + wo] = hi;
        *(half4v*)&sZ[1][gi * 8 + wo] = hj;
    }
    __syncthreads();

    float4* Zf4 = (float4*)Zf;
    const float4* s0 = (const float4*)sZ[0];
    const float4* s1 = (const float4*)sZ[1];
    const size_t gbi = (size_t)blockIdx.x * 1024;
    const size_t gbj = (size_t)(128 + blockIdx.x) * 1024;
#pragma unroll
    for (int it = 0; it < 4; ++it) {
        Zf4[gbi + tid + it * 256] = s0[tid + it * 256];
        Zf4[gbj + tid + it * 256] = s1[tid + it * 256];
    }
}

// DPP half-wave reduce: lane31 = sum(lanes 0..31), lane63 = sum(lanes 32..63).
__device__ __forceinline__ float half_sums(float x) {
    int t;
    t = __builtin_amdgcn_update_dpp(0, __builtin_bit_cast(int, x), 0x111, 0xf, 0xf, false);
    x += __builtin_bit_cast(float, t);
    t = __builtin_amdgcn_update_dpp(0, __builtin_bit_cast(int, x), 0x112, 0xf, 0xf, false);
    x += __builtin_bit_cast(float, t);
    t = __builtin_amdgcn_update_dpp(0, __builtin_bit_cast(int, x), 0x114, 0xf, 0xf, false);
    x += __builtin_bit_cast(float, t);
    t = __builtin_amdgcn_update_dpp(0, __builtin_bit_cast(int, x), 0x118, 0xf, 0xf, false);
    x += __builtin_bit_cast(float, t);
    t = __builtin_amdgcn_update_dpp(0, __builtin_bit_cast(int, x), 0x142, 0xa, 0xf, false);
    x += __builtin_bit_cast(float, t);
    return x;
}

// ---------------- Kernel 2: upper-tri sim-GEMM + exp + row/col sums ----------
// Grid: 528 blocks x 1024 thr (16 waves, 4x4). Block (rt,ct): 256x256 tile.
// Wave (wr,wc) = (wave>>2, wave&3): r8's verified 64x64 job verbatim —
// 2x2 accs, 4 coalesced 1KB fragment loads + 4 MFMAs per k-step, 1-deep
// prefetch, no k-loop barriers. Cross-wave L1 reuse: each A-group is read
// by 4 waves, each B-group by 4 waves, on the same CU.
__global__ __launch_bounds__(1024, 1) void nt_simexp(
    const _Float16* __restrict__ Zf, float* __restrict__ rowsum)
{
    __shared__ float colacc[TS];               // 1 KB (only LDS use)

    // Bijective XCD swizzle (528 % 8 == 0).
    const int bid = (blockIdx.x & 7) * (NBLK / 8) + (blockIdx.x >> 3);

    // Closed-form reverse-triangular map.
    const int t = NBLK - 1 - bid;
    int m = (int)((sqrtf((float)(8 * t + 1)) - 1.0f) * 0.5f);
    while ((m + 1) * (m + 2) / 2 <= t) ++m;
    while (m * (m + 1) / 2 > t) --m;
    const int rt = NT - 1 - m;
    const int ct = NT - 1 - (t - m * (m + 1) / 2);
    const bool diag = (rt == ct);

    const int tid = threadIdx.x;
    const int wave = tid >> 6;
    const int lane = tid & 63;
    const int lm = lane & 31;
    const int lh = lane >> 5;
    const int wr = wave >> 2;           // row quarter (A side), 0..3
    const int wc = wave & 3;            // col quarter (B side), 0..3

    const int rbase = rt * TS;          // A-side rows (output rows)
    const int cbase = ct * TS;          // B-side rows (output cols)

    if (tid < TS) colacc[tid] = 0.f;
    __syncthreads();                    // colacc init visible before epilogue

    // Fragment streams: row-groups of 32; wave's quadrant = 2 groups per side.
    const int ga0 = (rbase >> 5) + wr * 2;
    const int gb0 = (cbase >> 5) + wc * 2;
    const half8v* pa0 = (const half8v*)Zf + (size_t)ga0 * 1024 + lane;
    const half8v* pa1 = pa0 + 1024;
    const half8v* pb0 = (const half8v*)Zf + (size_t)gb0 * 1024 + lane;
    const half8v* pb1 = pb0 + 1024;

    floatx16 a00, a01, a10, a11;
#pragma unroll
    for (int r = 0; r < 16; ++r) { a00[r] = 0.f; a01[r] = 0.f; a10[r] = 0.f; a11[r] = 0.f; }

    half8v fa0 = pa0[0], fa1 = pa1[0], fb0 = pb0[0], fb1 = pb1[0];
#pragma unroll
    for (int ks = 0; ks < KSTEPS; ++ks) {
        half8v na0 = fa0, na1 = fa1, nb0 = fb0, nb1 = fb1;
        if (ks + 1 < KSTEPS) {
            na0 = pa0[(ks + 1) * 64];
            na1 = pa1[(ks + 1) * 64];
            nb0 = pb0[(ks + 1) * 64];
            nb1 = pb1[(ks + 1) * 64];
        }
        a00 = __builtin_amdgcn_mfma_f32_32x32x16_f16(fa0, fb0, a00, 0, 0, 0);
        a01 = __builtin_amdgcn_mfma_f32_32x32x16_f16(fa0, fb1, a01, 0, 0, 0);
        a10 = __builtin_amdgcn_mfma_f32_32x32x16_f16(fa1, fb0, a10, 0, 0, 0);
        a11 = __builtin_amdgcn_mfma_f32_32x32x16_f16(fa1, fb1, a11, 0, 0, 0);
        fa0 = na0; fa1 = na1; fb0 = nb0; fb1 = nb1;
    }

    // Epilogue (r8-verified verbatim): e = exp2(sim * 2*log2e). Per-lane reg
    // sums -> col-range rows (B side, lm); DPP -> row-range rows (A side).
    const float KEXP = 2.0f * 1.44269504088896340736f;
    float eb0 = 0.f, eb1 = 0.f;
#pragma unroll
    for (int tr = 0; tr < 2; ++tr) {
#pragma unroll
        for (int r = 0; r < 16; ++r) {
            const int mrow = (r & 3) + 8 * (r >> 2) + 4 * lh;
            float e0 = __builtin_amdgcn_exp2f((tr ? a10[r] : a00[r]) * KEXP);
            float e1 = __builtin_amdgcn_exp2f((tr ? a11[r] : a01[r]) * KEXP);
            // Diagonal element: global row == col -> wr==wc, tr==tc, mrow==lm.
            if (diag && (wr == wc) && (mrow == lm)) {
                if (tr == 0) e0 = 0.f; else e1 = 0.f;
            }
            eb0 += e0; eb1 += e1;
            if (!diag) {
                float s2 = half_sums(e0 + e1);   // lanes 31/63 hold half-sums
                if (lm == 31)
                    atomicAdd(&colacc[wr * 64 + tr * 32 + mrow], s2);  // ds_add
            }
        }
    }

    eb0 += __shfl_xor(eb0, 32);
    eb1 += __shfl_xor(eb1, 32);
    if (lane < 32) {
        atomicAdd(&rowsum[cbase + wc * 64 + lm], eb0);
        atomicAdd(&rowsum[cbase + wc * 64 + 32 + lm], eb1);
    }
    if (!diag) {
        __syncthreads();
        if (tid < TS) atomicAdd(&rowsum[rbase + tid], colacc[tid]);
    }
}

// ---------------- Kernel 3: finalize ----------------------------------------
__global__ __launch_bounds__(256) void nt_finalize(
    const float* __restrict__ rowsum, const float* __restrict__ pos,
    float* __restrict__ out)
{
    const int tid = threadIdx.x;
    float acc = 0.f;
#pragma unroll
    for (int it = 0; it < NN / 256; ++it)
        acc += __builtin_amdgcn_logf(rowsum[tid + it * 256]);   // log2
    float pacc = 0.f;
#pragma unroll
    for (int it = 0; it < BB / 256; ++it)
        pacc += pos[tid + it * 256];

#pragma unroll
    for (int off = 32; off > 0; off >>= 1) {
        acc  += __shfl_xor(acc,  off);
        pacc += __shfl_xor(pacc, off);
    }
    __shared__ float sa[4], sp[4];
    const int wave = tid >> 6;
    if ((tid & 63) == 0) { sa[wave] = acc; sp[wave] = pacc; }
    __syncthreads();
    if (tid == 0) {
        const float lntot = (sa[0] + sa[1] + sa[2] + sa[3]) * 0.6931471805599453f;
        const float ptot  = sp[0] + sp[1] + sp[2] + sp[3];
        out[0] = (lntot - 4.0f * ptot) * (1.0f / (float)NN);
    }
}

// ---------------- Launch ------------------------------------------------------
extern "C" void kernel_launch(void* const* d_in, const int* in_sizes, int n_in,
                              void* d_out, int out_size, void* d_ws, size_t ws_size,
                              hipStream_t stream) {
    const float* zi = (const float*)d_in[0];
    const float* zj = (const float*)d_in[1];
    float* out = (float*)d_out;

    _Float16* Zf = (_Float16*)d_ws;                                 // 4 MB
    float* rowsum = (float*)((char*)d_ws + (size_t)NN * DD * 2);    // 32 KB
    float* pos = rowsum + NN;                                       // 16 KB

    nt_normalize<<<BB / 32, 256, 0, stream>>>(zi, zj, Zf, pos, rowsum);
    nt_simexp<<<NBLK, 1024, 0, stream>>>((const _Float16*)Zf, rowsum);
    nt_finalize<<<1, 256, 0, stream>>>(rowsum, pos, out);
}